// Round 11
// baseline (293.647 us; speedup 1.0000x reference)
//
#include <hip/hip_runtime.h>
#include <hip/hip_bf16.h>

#define DIN 128
#define NEG_SLOPE 0.2f
#define PTILE 2048        // edges per partition tile
#define FCAP 8192         // fine-kernel LDS edge capacity (mean 4096, sigma~64)
#define CVT_BLKS 289      // blocks of cvt work in the merged cvt+hist kernel
#define LDSP 136          // LDS row stride in ushorts (272B, 16B-aligned)

typedef __attribute__((ext_vector_type(8))) short bf16x8;   // 8 bf16 = 4 VGPRs
typedef __attribute__((ext_vector_type(8))) unsigned short u16x8;
typedef __attribute__((ext_vector_type(4))) float f32x4;
typedef __attribute__((ext_vector_type(2))) float f32x2;
typedef __attribute__((ext_vector_type(4))) unsigned int u32x4;

__device__ __forceinline__ ushort f2bf(float f) {
  unsigned u = __float_as_uint(f);
  u += 0x7FFFu + ((u >> 16) & 1u);   // round-to-nearest-even
  return (ushort)(u >> 16);
}
__device__ __forceinline__ float bf2f(ushort u) {
  return __uint_as_float((unsigned)u << 16);
}
// unpack 2 packed bf16 (one dword) -> f32x2 {elem0, elem1}
__device__ __forceinline__ f32x2 bfpair(unsigned u) {
  f32x2 r;
  r.x = __uint_as_float(u << 16);
  r.y = __uint_as_float(u & 0xFFFF0000u);
  return r;
}

// ---------------------------------------------------------------------------
// merged prep: blocks [0,CVT_BLKS) convert weights -> bf16 transposed;
// blocks [CVT_BLKS,...) build the 256-bucket dst histogram (bucket=dst>>8).
// ghist zeroed by hipMemsetAsync before this kernel.
// ---------------------------------------------------------------------------
__global__ __launch_bounds__(256) void cvt_hist_kernel(
    const float* __restrict__ Wl, const float* __restrict__ Wr,
    const float* __restrict__ W1, const float* __restrict__ W2,
    const float* __restrict__ W3,
    ushort* __restrict__ WlT, ushort* __restrict__ WrT,
    ushort* __restrict__ W1T, ushort* __restrict__ W2T,
    ushort* __restrict__ W3T,
    const int* __restrict__ ei, int* __restrict__ ghist, int E) {
  if (blockIdx.x < CVT_BLKS) {
    int i = blockIdx.x * 256 + threadIdx.x;
    if (i < 16384) {
      int k = i >> 7, c = i & 127; WlT[c * 128 + k] = f2bf(Wl[i]);
    } else if (i < 32768) {
      int j = i - 16384; int k = j >> 7, c = j & 127; WrT[c * 128 + k] = f2bf(Wr[j]);
    } else if (i < 49152) {
      int j = i - 32768; int k = j >> 7, c = j & 127; W1T[c * 128 + k] = f2bf(W1[j]);
    } else if (i < 65536) {
      int j = i - 49152; int k = j >> 7, c = j & 127; W2T[c * 128 + k] = f2bf(W2[j]);
    } else if (i < 73728) {
      int j = i - 65536; int k = j >> 6, c = j & 63; W3T[c * 128 + k] = f2bf(W3[j]);
    }
  } else {
    __shared__ int h[256];
    h[threadIdx.x] = 0;
    __syncthreads();
    int tile = blockIdx.x - CVT_BLKS;
    for (int e = tile * PTILE + threadIdx.x;
         e < min(E, (tile + 1) * PTILE); e += 256)
      atomicAdd(&h[ei[E + e] >> 8], 1);
    __syncthreads();
    if (h[threadIdx.x] > 0) atomicAdd(&ghist[threadIdx.x], h[threadIdx.x]);
  }
}

// 1 block: exclusive scan of ghist[256] -> cum[257]; cursor[b] = cum[b].
__global__ __launch_bounds__(256) void scan_small_kernel(
    const int* __restrict__ ghist, int* __restrict__ cum,
    int* __restrict__ cursor) {
  __shared__ int sh[256];
  int tid = threadIdx.x;
  int v = ghist[tid];
  sh[tid] = v;
  __syncthreads();
  for (int d = 1; d < 256; d <<= 1) {
    int t = (tid >= d) ? sh[tid - d] : 0;
    __syncthreads();
    sh[tid] += t;
    __syncthreads();
  }
  int exc = sh[tid] - v;
  cum[tid] = exc;
  cursor[tid] = exc;
  if (tid == 255) cum[256] = sh[255];
}

// ---------------------------------------------------------------------------
// MEGA kernel: blocks [0,nblk_lin) run the lin_lr MFMA GEMM; the rest run
// the partition pass (independent work, overlapped on one dispatch).
// ---------------------------------------------------------------------------
__global__ __launch_bounds__(256) void lin_partition_kernel(
    const float* __restrict__ x,
    const ushort* __restrict__ WlT, const float* __restrict__ bl,
    const ushort* __restrict__ WrT, const float* __restrict__ br,
    ushort* __restrict__ xl, ushort* __restrict__ xr, int n, int nblk_lin,
    const int* __restrict__ ei, unsigned* __restrict__ part,
    int* __restrict__ cursor, int E) {
  if ((int)blockIdx.x < nblk_lin) {
    // ---- lin_lr: xl = x@Wl+bl ; xr = x@Wr+br (bf16 out) ----
    const int tid = threadIdx.x;
    const int wv = tid >> 6, lane = tid & 63;
    const int m = lane & 15, quad = lane >> 4;
    const int colbase = (wv & 1) * 64;
    const int nodew = blockIdx.x * 32 + (wv >> 1) * 16;
    int arow = nodew + m; if (arow >= n) arow = n - 1;
    f32x4 accl[4], accr[4];
#pragma unroll
    for (int nt = 0; nt < 4; nt++) { accl[nt] = (f32x4){0,0,0,0}; accr[nt] = (f32x4){0,0,0,0}; }
#pragma unroll
    for (int kk = 0; kk < 4; kk++) {
      int k0 = kk * 32 + quad * 8;
      const float4* xp = (const float4*)(x + (long)arow * 128 + k0);
      float4 x0 = xp[0], x1 = xp[1];
      bf16x8 af;
      af[0] = (short)f2bf(x0.x); af[1] = (short)f2bf(x0.y);
      af[2] = (short)f2bf(x0.z); af[3] = (short)f2bf(x0.w);
      af[4] = (short)f2bf(x1.x); af[5] = (short)f2bf(x1.y);
      af[6] = (short)f2bf(x1.z); af[7] = (short)f2bf(x1.w);
#pragma unroll
      for (int nt = 0; nt < 4; nt++) {
        int brow = colbase + nt * 16 + m;
        bf16x8 bl8 = *(const bf16x8*)(WlT + brow * 128 + k0);
        bf16x8 br8 = *(const bf16x8*)(WrT + brow * 128 + k0);
        accl[nt] = __builtin_amdgcn_mfma_f32_16x16x32_bf16(af, bl8, accl[nt], 0, 0, 0);
        accr[nt] = __builtin_amdgcn_mfma_f32_16x16x32_bf16(af, br8, accr[nt], 0, 0, 0);
      }
    }
#pragma unroll
    for (int nt = 0; nt < 4; nt++) {
      int col = colbase + nt * 16 + m;
      float vbl = bl[col], vbr = br[col];
#pragma unroll
      for (int r = 0; r < 4; r++) {
        int node = nodew + quad * 4 + r;
        if (node < n) {
          xl[(long)node * 128 + col] = f2bf(accl[nt][r] + vbl);
          xr[(long)node * 128 + col] = f2bf(accr[nt][r] + vbr);
        }
      }
    }
  } else {
    // ---- partition: tile -> LDS bucket-grouped reorder -> dense runs ----
    __shared__ int hist[256], pref[256], sexcl[256], curs[256], gbase[256];
    __shared__ unsigned buf[PTILE];
    const int tid = threadIdx.x;
    const int tile0 = ((int)blockIdx.x - nblk_lin) * PTILE;
    const int tcount = min(PTILE, E - tile0);
    hist[tid] = 0;
    __syncthreads();
    unsigned pk[PTILE / 256];
    int cnt = 0;
    for (int i = tid; i < tcount; i += 256) {
      int e = tile0 + i;
      int s = ei[e], d = ei[E + e];
      unsigned p = ((unsigned)d << 16) | (unsigned)s;
      pk[cnt++] = p;
      atomicAdd(&hist[d >> 8], 1);
    }
    __syncthreads();
    int v = hist[tid];
    pref[tid] = v;
    __syncthreads();
    for (int d = 1; d < 256; d <<= 1) {
      int t = (tid >= d) ? pref[tid - d] : 0;
      __syncthreads();
      pref[tid] += t;
      __syncthreads();
    }
    int exc = pref[tid] - v;
    sexcl[tid] = exc;
    curs[tid] = exc;
    gbase[tid] = (v > 0) ? atomicAdd(&cursor[tid], v) : 0;
    __syncthreads();
    for (int j = 0; j < cnt; j++) {
      int b = pk[j] >> 24;
      int pos = atomicAdd(&curs[b], 1);
      buf[pos] = pk[j];
    }
    __syncthreads();
    for (int i = tid; i < tcount; i += 256) {
      unsigned p = buf[i];
      int b = p >> 24;
      part[gbase[b] + (i - sexcl[b])] = p;
    }
  }
}

// per-bucket: node hist + scan -> offsets; LDS reorder -> coalesced ssrc
// (ushort: src < 65536). 512 threads.
__global__ __launch_bounds__(512) void fine_kernel(
    const unsigned* __restrict__ part, const int* __restrict__ cum,
    int* __restrict__ offsets, ushort* __restrict__ ssrc,
    int N, int E, int nbuck) {
  __shared__ int hist[256], pref[256], curs[256];
  __shared__ unsigned buf[FCAP], buf2[FCAP];
  const int tid = threadIdx.x;
  const int b = blockIdx.x;
  const int seg0 = cum[b];
  const int len = min(cum[b + 1] - seg0, FCAP);
  if (tid < 256) hist[tid] = 0;
  __syncthreads();
  for (int i = tid; i < len; i += 512) {
    unsigned p = part[seg0 + i];
    buf[i] = p;
    atomicAdd(&hist[(p >> 16) & 255], 1);
  }
  __syncthreads();
  int v = (tid < 256) ? hist[tid] : 0;
  if (tid < 256) pref[tid] = v;
  __syncthreads();
  for (int d = 1; d < 256; d <<= 1) {
    int t = (tid >= d && tid < 256) ? pref[tid - d] : 0;
    __syncthreads();
    if (tid < 256) pref[tid] += t;
    __syncthreads();
  }
  if (tid < 256) {
    int exc = pref[tid] - v;
    curs[tid] = exc;
    int node = b * 256 + tid;
    if (node < N) offsets[node] = seg0 + exc;
  }
  if (b == nbuck - 1 && tid == 0) offsets[N] = E;
  __syncthreads();
  for (int i = tid; i < len; i += 512) {
    unsigned p = buf[i];
    int pos = atomicAdd(&curs[(p >> 16) & 255], 1);
    buf2[pos] = p;
  }
  __syncthreads();
  for (int i = tid; i < len; i += 512)
    ssrc[seg0 + i] = (ushort)(buf2[i] & 0xFFFFu);
}

// ---------------------------------------------------------------------------
// FUSED GATv2 aggregation + 3-layer MLP. One block = 64 contiguous nodes
// (4 waves x 16 nodes each). Phase A is R7's proven aggregation body (global
// CSR from fine_kernel — NOT R8's redundant in-block scan); h rows land in
// LDS hbuf (never global). Phase B is the MFMA MLP on the 64 LDS rows; each
// wave touches only its own 16 rows, so no intra-MLP barriers. Co-resident
// blocks in different phases overlap MFMA with gather stalls (m114).
// ---------------------------------------------------------------------------
__global__ __launch_bounds__(256) void aggr_mlp_kernel(
    const ushort* __restrict__ xl, const ushort* __restrict__ xr,
    const float* __restrict__ att, const float* __restrict__ bg,
    const int* __restrict__ offsets, const ushort* __restrict__ ssrc,
    const ushort* __restrict__ W1T, const float* __restrict__ b1,
    const ushort* __restrict__ W2T, const float* __restrict__ b2,
    const ushort* __restrict__ W3T, const float* __restrict__ b3,
    float* __restrict__ out, int n) {
  __shared__ ushort hbuf[64][LDSP];
  const int tid = threadIdx.x;
  const int wv = tid >> 6, lane = tid & 63;
  const int eg = lane >> 4, sl = lane & 15;
  const int node0 = blockIdx.x * 64;
  f32x2 av2[4], gv2[4];
  {
    const float4* ap = (const float4*)(att + sl * 8);
    float4 a0 = ap[0], a1 = ap[1];
    av2[0] = (f32x2){a0.x, a0.y}; av2[1] = (f32x2){a0.z, a0.w};
    av2[2] = (f32x2){a1.x, a1.y}; av2[3] = (f32x2){a1.z, a1.w};
    const float4* bp = (const float4*)(bg + sl * 8);
    float4 g0 = bp[0], g1 = bp[1];
    gv2[0] = (f32x2){g0.x, g0.y}; gv2[1] = (f32x2){g0.z, g0.w};
    gv2[2] = (f32x2){g1.x, g1.y}; gv2[3] = (f32x2){g1.z, g1.w};
  }
  const ushort* xls = xl + sl * 8;

  // ---- phase A: per-node aggregation, 16 nodes per wave ----
  for (int t = 0; t < 16; t++) {
    const int ln = (wv << 4) + t;
    const int node = node0 + ln;
    if (node >= n) {
      if (eg == 0) {
        u16x8 z;
#pragma unroll
        for (int j = 0; j < 8; j++) z[j] = 0;
        *(u16x8*)(&hbuf[ln][sl * 8]) = z;
      }
      continue;
    }
    f32x2 r2[4], acc2[4];
    u32x4 rv = *(const u32x4*)(xr + (long)node * 128 + sl * 8);
    u32x4 lv = *(const u32x4*)(xls + (long)node * 128);
    float denom;
    {
      f32x2 t2 = {0.f, 0.f};
      f32x2 l2[4];
#pragma unroll
      for (int jp = 0; jp < 4; jp++) {
        r2[jp] = bfpair(rv[jp]);
        l2[jp] = bfpair(lv[jp]);
        f32x2 v = l2[jp] + r2[jp];
        t2 += __builtin_elementwise_max(v, NEG_SLOPE * v) * av2[jp];
      }
      float tt = t2.x + t2.y;
#pragma unroll
      for (int off = 1; off < 16; off <<= 1) tt += __shfl_xor(tt, off);
      float es = __expf(tt);             // self-loop weight
      denom = (eg == 0) ? es : 0.f;
#pragma unroll
      for (int jp = 0; jp < 4; jp++)
        acc2[jp] = (eg == 0) ? es * l2[jp] : (f32x2){0.f, 0.f};
    }
    const int beg = offsets[node];
    const int end = offsets[node + 1];
    for (int p = beg; p < end; p += 8) {
      int ia = p + 2 * eg;
      bool va = ia < end, vb = ia + 1 < end;
      int sa = va ? (int)ssrc[ia] : node;   // clamp: safe in-bounds row
      int sb = vb ? (int)ssrc[ia + 1] : node;
      u32x4 uva = *(const u32x4*)(xls + (long)sa * 128);
      u32x4 uvb = *(const u32x4*)(xls + (long)sb * 128);
      f32x2 ua2[4], ub2[4];
      f32x2 ta2 = {0.f, 0.f}, tb2 = {0.f, 0.f};
#pragma unroll
      for (int jp = 0; jp < 4; jp++) {
        ua2[jp] = bfpair(uva[jp]);
        ub2[jp] = bfpair(uvb[jp]);
        f32x2 wa = ua2[jp] + r2[jp];
        f32x2 wb = ub2[jp] + r2[jp];
        ta2 += __builtin_elementwise_max(wa, NEG_SLOPE * wa) * av2[jp];
        tb2 += __builtin_elementwise_max(wb, NEG_SLOPE * wb) * av2[jp];
      }
      float ta = ta2.x + ta2.y, tb = tb2.x + tb2.y;
#pragma unroll
      for (int off = 1; off < 16; off <<= 1) {
        ta += __shfl_xor(ta, off);
        tb += __shfl_xor(tb, off);
      }
      float ea = va ? __expf(ta) : 0.f;
      float eb = vb ? __expf(tb) : 0.f;
      denom += ea + eb;
#pragma unroll
      for (int jp = 0; jp < 4; jp++)
        acc2[jp] += ea * ua2[jp] + eb * ub2[jp];
    }
    // combine the 4 edge-subgroup replicas
#pragma unroll
    for (int jp = 0; jp < 4; jp++) {
      acc2[jp].x += __shfl_xor(acc2[jp].x, 16);
      acc2[jp].y += __shfl_xor(acc2[jp].y, 16);
      acc2[jp].x += __shfl_xor(acc2[jp].x, 32);
      acc2[jp].y += __shfl_xor(acc2[jp].y, 32);
    }
    denom += __shfl_xor(denom, 16);
    denom += __shfl_xor(denom, 32);
    if (eg == 0) {
      float inv = 1.0f / denom;
      u16x8 o;
#pragma unroll
      for (int jp = 0; jp < 4; jp++) {
        f32x2 hv = acc2[jp] * inv + gv2[jp];
        o[2 * jp]     = f2bf(hv.x);
        o[2 * jp + 1] = f2bf(hv.y);
      }
      *(u16x8*)(&hbuf[ln][sl * 8]) = o;
    }
  }
  __syncthreads();

  // ---- phase B: 3-layer MFMA MLP; each wave owns rows [wv*16, wv*16+16) ----
  const int m = lane & 15, quad = lane >> 4;
  const int arow = (wv << 4) + m;
  bf16x8 af[4];
  f32x4 acc[8];
  // layer 1: hbuf @ W1 + b1, relu -> hbuf
#pragma unroll
  for (int kk = 0; kk < 4; kk++)
    af[kk] = *(const bf16x8*)(&hbuf[arow][kk * 32 + quad * 8]);
#pragma unroll
  for (int nt = 0; nt < 8; nt++) acc[nt] = (f32x4){0,0,0,0};
#pragma unroll
  for (int kk = 0; kk < 4; kk++) {
    int k0 = kk * 32 + quad * 8;
#pragma unroll
    for (int nt = 0; nt < 8; nt++) {
      bf16x8 b8 = *(const bf16x8*)(W1T + (nt * 16 + m) * 128 + k0);
      acc[nt] = __builtin_amdgcn_mfma_f32_16x16x32_bf16(af[kk], b8, acc[nt], 0, 0, 0);
    }
  }
#pragma unroll
  for (int nt = 0; nt < 8; nt++) {
    int col = nt * 16 + m;
    float bv = b1[col];
#pragma unroll
    for (int r = 0; r < 4; r++)
      hbuf[(wv << 4) + quad * 4 + r][col] = f2bf(fmaxf(acc[nt][r] + bv, 0.f));
  }
  // layer 2: hbuf @ W2 + b2, relu -> hbuf (wave-private rows, no barrier)
#pragma unroll
  for (int kk = 0; kk < 4; kk++)
    af[kk] = *(const bf16x8*)(&hbuf[arow][kk * 32 + quad * 8]);
#pragma unroll
  for (int nt = 0; nt < 8; nt++) acc[nt] = (f32x4){0,0,0,0};
#pragma unroll
  for (int kk = 0; kk < 4; kk++) {
    int k0 = kk * 32 + quad * 8;
#pragma unroll
    for (int nt = 0; nt < 8; nt++) {
      bf16x8 b8 = *(const bf16x8*)(W2T + (nt * 16 + m) * 128 + k0);
      acc[nt] = __builtin_amdgcn_mfma_f32_16x16x32_bf16(af[kk], b8, acc[nt], 0, 0, 0);
    }
  }
#pragma unroll
  for (int nt = 0; nt < 8; nt++) {
    int col = nt * 16 + m;
    float bv = b2[col];
#pragma unroll
    for (int r = 0; r < 4; r++)
      hbuf[(wv << 4) + quad * 4 + r][col] = f2bf(fmaxf(acc[nt][r] + bv, 0.f));
  }
  // layer 3: hbuf @ W3 + b3 -> out (fp32, 64 cols)
#pragma unroll
  for (int kk = 0; kk < 4; kk++)
    af[kk] = *(const bf16x8*)(&hbuf[arow][kk * 32 + quad * 8]);
  f32x4 acc3[4];
#pragma unroll
  for (int nt = 0; nt < 4; nt++) acc3[nt] = (f32x4){0,0,0,0};
#pragma unroll
  for (int kk = 0; kk < 4; kk++) {
    int k0 = kk * 32 + quad * 8;
#pragma unroll
    for (int nt = 0; nt < 4; nt++) {
      bf16x8 b8 = *(const bf16x8*)(W3T + (nt * 16 + m) * 128 + k0);
      acc3[nt] = __builtin_amdgcn_mfma_f32_16x16x32_bf16(af[kk], b8, acc3[nt], 0, 0, 0);
    }
  }
#pragma unroll
  for (int nt = 0; nt < 4; nt++) {
    int col = nt * 16 + m;
    float bv = b3[col];
#pragma unroll
    for (int r = 0; r < 4; r++) {
      int node = node0 + (wv << 4) + quad * 4 + r;
      if (node < n) out[(long)node * 64 + col] = acc3[nt][r] + bv;
    }
  }
}

extern "C" void kernel_launch(void* const* d_in, const int* in_sizes, int n_in,
                              void* d_out, int out_size, void* d_ws, size_t ws_size,
                              hipStream_t stream) {
  const float* x   = (const float*)d_in[0];
  const int*   ei  = (const int*)d_in[1];
  const float* Wl  = (const float*)d_in[2];
  const float* bl  = (const float*)d_in[3];
  const float* Wr  = (const float*)d_in[4];
  const float* br  = (const float*)d_in[5];
  const float* att = (const float*)d_in[6];
  const float* bg  = (const float*)d_in[7];
  const float* W1  = (const float*)d_in[8];
  const float* b1  = (const float*)d_in[9];
  const float* W2  = (const float*)d_in[10];
  const float* b2  = (const float*)d_in[11];
  const float* W3  = (const float*)d_in[12];
  const float* b3  = (const float*)d_in[13];
  float* out = (float*)d_out;

  const int N = in_sizes[0] / DIN;
  const int E = in_sizes[1] / 2;
  const int nbuck = (N + 255) >> 8;

  // workspace layout, every array 256B-aligned (row gathers must not split
  // cachelines)
  char* ws = (char*)d_ws;
  size_t off = 0;
  auto alloc = [&](size_t bytes) {
    void* p = ws + off;
    off += (bytes + 255) & ~(size_t)255;
    return p;
  };
  int* ghist     = (int*)alloc(256 * 4);
  int* cum       = (int*)alloc(257 * 4);
  int* cursor    = (int*)alloc(256 * 4);
  int* offsets   = (int*)alloc(((size_t)N + 4) * 4);
  unsigned* part = (unsigned*)alloc((size_t)E * 4);
  ushort* ssrc   = (ushort*)alloc(((size_t)E + 32) * 2);
  ushort* xlb    = (ushort*)alloc((size_t)N * DIN * 2);
  ushort* xrb    = (ushort*)alloc((size_t)N * DIN * 2);
  ushort* WlT    = (ushort*)alloc(16384 * 2);
  ushort* WrT    = (ushort*)alloc(16384 * 2);
  ushort* W1T    = (ushort*)alloc(16384 * 2);
  ushort* W2T    = (ushort*)alloc(16384 * 2);
  ushort* W3T    = (ushort*)alloc(8192 * 2);
  (void)ws_size;

  hipMemsetAsync(ghist, 0, 256 * 4, stream);

  int ntile = (E + PTILE - 1) / PTILE;
  cvt_hist_kernel<<<CVT_BLKS + ntile, 256, 0, stream>>>(
      Wl, Wr, W1, W2, W3, WlT, WrT, W1T, W2T, W3T, ei, ghist, E);

  scan_small_kernel<<<1, 256, 0, stream>>>(ghist, cum, cursor);

  int nblk32 = (N + 31) / 32;
  lin_partition_kernel<<<nblk32 + ntile, 256, 0, stream>>>(
      x, WlT, bl, WrT, br, xlb, xrb, N, nblk32, ei, part, cursor, E);

  fine_kernel<<<nbuck, 512, 0, stream>>>(part, cum, offsets, ssrc, N, E, nbuck);

  int nblk64 = (N + 63) / 64;
  aggr_mlp_kernel<<<nblk64, 256, 0, stream>>>(
      xlb, xrb, att, bg, offsets, ssrc,
      W1T, b1, W2T, b2, W3T, b3, out, N);
}

// Round 12
// 243.458 us; speedup vs baseline: 1.2062x; 1.2062x over previous
//
#include <hip/hip_runtime.h>
#include <hip/hip_bf16.h>

#define DIN 128
#define NEG_SLOPE 0.2f
#define PTILE 2048        // edges per partition tile
#define FCAP 8192         // fine-kernel LDS edge capacity (mean 4096, sigma~64)
#define CVT_BLKS 289      // blocks of cvt work in the merged cvt+hist kernel
#define LDSP 136          // LDS row stride in ushorts (272B, 16B-aligned)

typedef __attribute__((ext_vector_type(8))) short bf16x8;   // 8 bf16 = 4 VGPRs
typedef __attribute__((ext_vector_type(8))) unsigned short u16x8;
typedef __attribute__((ext_vector_type(4))) float f32x4;
typedef __attribute__((ext_vector_type(2))) float f32x2;
typedef __attribute__((ext_vector_type(4))) unsigned int u32x4;

__device__ __forceinline__ ushort f2bf(float f) {
  unsigned u = __float_as_uint(f);
  u += 0x7FFFu + ((u >> 16) & 1u);   // round-to-nearest-even
  return (ushort)(u >> 16);
}
__device__ __forceinline__ float bf2f(ushort u) {
  return __uint_as_float((unsigned)u << 16);
}
// unpack 2 packed bf16 (one dword) -> f32x2 {elem0, elem1}
__device__ __forceinline__ f32x2 bfpair(unsigned u) {
  f32x2 r;
  r.x = __uint_as_float(u << 16);
  r.y = __uint_as_float(u & 0xFFFF0000u);
  return r;
}

// ---------------------------------------------------------------------------
// merged prep: blocks [0,CVT_BLKS) convert weights -> bf16 transposed;
// blocks [CVT_BLKS,...) build the 256-bucket dst histogram (bucket=dst>>8).
// ghist zeroed by hipMemsetAsync before this kernel.
// ---------------------------------------------------------------------------
__global__ __launch_bounds__(256) void cvt_hist_kernel(
    const float* __restrict__ Wl, const float* __restrict__ Wr,
    const float* __restrict__ W1, const float* __restrict__ W2,
    const float* __restrict__ W3,
    ushort* __restrict__ WlT, ushort* __restrict__ WrT,
    ushort* __restrict__ W1T, ushort* __restrict__ W2T,
    ushort* __restrict__ W3T,
    const int* __restrict__ ei, int* __restrict__ ghist, int E) {
  if (blockIdx.x < CVT_BLKS) {
    int i = blockIdx.x * 256 + threadIdx.x;
    if (i < 16384) {
      int k = i >> 7, c = i & 127; WlT[c * 128 + k] = f2bf(Wl[i]);
    } else if (i < 32768) {
      int j = i - 16384; int k = j >> 7, c = j & 127; WrT[c * 128 + k] = f2bf(Wr[j]);
    } else if (i < 49152) {
      int j = i - 32768; int k = j >> 7, c = j & 127; W1T[c * 128 + k] = f2bf(W1[j]);
    } else if (i < 65536) {
      int j = i - 49152; int k = j >> 7, c = j & 127; W2T[c * 128 + k] = f2bf(W2[j]);
    } else if (i < 73728) {
      int j = i - 65536; int k = j >> 6, c = j & 63; W3T[c * 128 + k] = f2bf(W3[j]);
    }
  } else {
    __shared__ int h[256];
    h[threadIdx.x] = 0;
    __syncthreads();
    int tile = blockIdx.x - CVT_BLKS;
    for (int e = tile * PTILE + threadIdx.x;
         e < min(E, (tile + 1) * PTILE); e += 256)
      atomicAdd(&h[ei[E + e] >> 8], 1);
    __syncthreads();
    if (h[threadIdx.x] > 0) atomicAdd(&ghist[threadIdx.x], h[threadIdx.x]);
  }
}

// 1 block: exclusive scan of ghist[256] -> cum[257]; cursor[b] = cum[b].
__global__ __launch_bounds__(256) void scan_small_kernel(
    const int* __restrict__ ghist, int* __restrict__ cum,
    int* __restrict__ cursor) {
  __shared__ int sh[256];
  int tid = threadIdx.x;
  int v = ghist[tid];
  sh[tid] = v;
  __syncthreads();
  for (int d = 1; d < 256; d <<= 1) {
    int t = (tid >= d) ? sh[tid - d] : 0;
    __syncthreads();
    sh[tid] += t;
    __syncthreads();
  }
  int exc = sh[tid] - v;
  cum[tid] = exc;
  cursor[tid] = exc;
  if (tid == 255) cum[256] = sh[255];
}

// ---------------------------------------------------------------------------
// MEGA kernel: blocks [0,nblk_lin) run the lin_lr MFMA GEMM (x staged
// through LDS with fully-coalesced loads — the R7 version read A-fragments
// at 512B row stride, 64 scattered segments per instruction); the rest run
// the partition pass (independent work, overlapped on one dispatch).
// ---------------------------------------------------------------------------
__global__ __launch_bounds__(256) void lin_partition_kernel(
    const float* __restrict__ x,
    const ushort* __restrict__ WlT, const float* __restrict__ bl,
    const ushort* __restrict__ WrT, const float* __restrict__ br,
    ushort* __restrict__ xl, ushort* __restrict__ xr, int n, int nblk_lin,
    const int* __restrict__ ei, unsigned* __restrict__ part,
    int* __restrict__ cursor, int E) {
  if ((int)blockIdx.x < nblk_lin) {
    // ---- lin_lr: xl = x@Wl+bl ; xr = x@Wr+br (bf16 out) ----
    __shared__ ushort xs[32][LDSP];
    const int tid = threadIdx.x;
    const int node0 = blockIdx.x * 32;
    for (int i = tid; i < 1024; i += 256) {   // 32 rows x 32 float4, coalesced
      int row = i >> 5, c4 = i & 31;
      int node = node0 + row;
      float4 v = {0.f, 0.f, 0.f, 0.f};
      if (node < n) v = ((const float4*)(x + (long)node * 128))[c4];
      ushort4 o;
      o.x = f2bf(v.x); o.y = f2bf(v.y); o.z = f2bf(v.z); o.w = f2bf(v.w);
      *(ushort4*)(&xs[row][c4 * 4]) = o;
    }
    __syncthreads();
    const int wv = tid >> 6, lane = tid & 63;
    const int m = lane & 15, quad = lane >> 4;
    const int colbase = (wv & 1) * 64;
    const int ng = wv >> 1;
    const int nodew = node0 + ng * 16;
    bf16x8 af[4];
#pragma unroll
    for (int kk = 0; kk < 4; kk++)
      af[kk] = *(const bf16x8*)(&xs[ng * 16 + m][kk * 32 + quad * 8]);
    f32x4 accl[4], accr[4];
#pragma unroll
    for (int nt = 0; nt < 4; nt++) { accl[nt] = (f32x4){0,0,0,0}; accr[nt] = (f32x4){0,0,0,0}; }
#pragma unroll
    for (int kk = 0; kk < 4; kk++) {
      int k0 = kk * 32 + quad * 8;
#pragma unroll
      for (int nt = 0; nt < 4; nt++) {
        int brow = colbase + nt * 16 + m;
        bf16x8 bl8 = *(const bf16x8*)(WlT + brow * 128 + k0);
        bf16x8 br8 = *(const bf16x8*)(WrT + brow * 128 + k0);
        accl[nt] = __builtin_amdgcn_mfma_f32_16x16x32_bf16(af[kk], bl8, accl[nt], 0, 0, 0);
        accr[nt] = __builtin_amdgcn_mfma_f32_16x16x32_bf16(af[kk], br8, accr[nt], 0, 0, 0);
      }
    }
#pragma unroll
    for (int nt = 0; nt < 4; nt++) {
      int col = colbase + nt * 16 + m;
      float vbl = bl[col], vbr = br[col];
#pragma unroll
      for (int r = 0; r < 4; r++) {
        int node = nodew + quad * 4 + r;
        if (node < n) {
          xl[(long)node * 128 + col] = f2bf(accl[nt][r] + vbl);
          xr[(long)node * 128 + col] = f2bf(accr[nt][r] + vbr);
        }
      }
    }
  } else {
    // ---- partition: tile -> LDS bucket-grouped reorder -> dense runs ----
    __shared__ int hist[256], pref[256], sexcl[256], curs[256], gbase[256];
    __shared__ unsigned buf[PTILE];
    const int tid = threadIdx.x;
    const int tile0 = ((int)blockIdx.x - nblk_lin) * PTILE;
    const int tcount = min(PTILE, E - tile0);
    hist[tid] = 0;
    __syncthreads();
    unsigned pk[PTILE / 256];
    int cnt = 0;
    for (int i = tid; i < tcount; i += 256) {
      int e = tile0 + i;
      int s = ei[e], d = ei[E + e];
      unsigned p = ((unsigned)d << 16) | (unsigned)s;
      pk[cnt++] = p;
      atomicAdd(&hist[d >> 8], 1);
    }
    __syncthreads();
    int v = hist[tid];
    pref[tid] = v;
    __syncthreads();
    for (int d = 1; d < 256; d <<= 1) {
      int t = (tid >= d) ? pref[tid - d] : 0;
      __syncthreads();
      pref[tid] += t;
      __syncthreads();
    }
    int exc = pref[tid] - v;
    sexcl[tid] = exc;
    curs[tid] = exc;
    gbase[tid] = (v > 0) ? atomicAdd(&cursor[tid], v) : 0;
    __syncthreads();
    for (int j = 0; j < cnt; j++) {
      int b = pk[j] >> 24;
      int pos = atomicAdd(&curs[b], 1);
      buf[pos] = pk[j];
    }
    __syncthreads();
    for (int i = tid; i < tcount; i += 256) {
      unsigned p = buf[i];
      int b = p >> 24;
      part[gbase[b] + (i - sexcl[b])] = p;
    }
  }
}

// per-bucket: node hist + scan -> offsets; LDS reorder -> coalesced ssrc
// (ushort: src < 65536). 1024 threads: only 196 blocks exist, so per-block
// thread count is the only parallelism lever; quarters the strided loops.
__global__ __launch_bounds__(1024) void fine_kernel(
    const unsigned* __restrict__ part, const int* __restrict__ cum,
    int* __restrict__ offsets, ushort* __restrict__ ssrc,
    int N, int E, int nbuck) {
  __shared__ int hist[256], pref[256], curs[256];
  __shared__ unsigned buf[FCAP], buf2[FCAP];
  const int tid = threadIdx.x;
  const int b = blockIdx.x;
  const int seg0 = cum[b];
  const int len = min(cum[b + 1] - seg0, FCAP);
  if (tid < 256) hist[tid] = 0;
  __syncthreads();
  for (int i = tid; i < len; i += 1024) {
    unsigned p = part[seg0 + i];
    buf[i] = p;
    atomicAdd(&hist[(p >> 16) & 255], 1);
  }
  __syncthreads();
  int v = (tid < 256) ? hist[tid] : 0;
  if (tid < 256) pref[tid] = v;
  __syncthreads();
  for (int d = 1; d < 256; d <<= 1) {
    int t = (tid >= d && tid < 256) ? pref[tid - d] : 0;
    __syncthreads();
    if (tid < 256) pref[tid] += t;
    __syncthreads();
  }
  if (tid < 256) {
    int exc = pref[tid] - v;
    curs[tid] = exc;
    int node = b * 256 + tid;
    if (node < N) offsets[node] = seg0 + exc;
  }
  if (b == nbuck - 1 && tid == 0) offsets[N] = E;
  __syncthreads();
  for (int i = tid; i < len; i += 1024) {
    unsigned p = buf[i];
    int pos = atomicAdd(&curs[(p >> 16) & 255], 1);
    buf2[pos] = p;
  }
  __syncthreads();
  for (int i = tid; i < len; i += 1024)
    ssrc[seg0 + i] = (ushort)(buf2[i] & 0xFFFFu);
}

// ---------------------------------------------------------------------------
// Fused per-node GATv2 (R7's proven best body, byte-identical): one wave per
// dst node; 16 lanes/edge, 4 edge subgroups, 8 edge-slots/iter. Packed f32x2
// math, no max-tracking (scores bounded << 88). ssrc is ushort.
// Latency hiding comes from wave oversubscription (12.5k blocks) — R8/R11
// proved fusing this into fewer blocks starves TLP.
// ---------------------------------------------------------------------------
__global__ __launch_bounds__(256) void node_aggr_kernel(
    const ushort* __restrict__ xl, const ushort* __restrict__ xr,
    const float* __restrict__ att, const float* __restrict__ bg,
    const int* __restrict__ offsets, const ushort* __restrict__ ssrc,
    ushort* __restrict__ h, int n) {
  int wave = (int)((blockIdx.x * (long)blockDim.x + threadIdx.x) >> 6);
  int lane = threadIdx.x & 63;
  if (wave >= n) return;
  const int node = wave;
  const int eg = lane >> 4, sl = lane & 15;
  f32x2 av2[4], r2[4], acc2[4];
  {
    const float4* ap = (const float4*)(att + sl * 8);
    float4 a0 = ap[0], a1 = ap[1];
    av2[0] = (f32x2){a0.x, a0.y}; av2[1] = (f32x2){a0.z, a0.w};
    av2[2] = (f32x2){a1.x, a1.y}; av2[3] = (f32x2){a1.z, a1.w};
  }
  const ushort* xls = xl + sl * 8;
  u32x4 rv = *(const u32x4*)(xr + (long)node * 128 + sl * 8);
  u32x4 lv = *(const u32x4*)(xls + (long)node * 128);
  float denom;
  {
    f32x2 t2 = {0.f, 0.f};
    f32x2 l2[4];
#pragma unroll
    for (int jp = 0; jp < 4; jp++) {
      r2[jp] = bfpair(rv[jp]);
      l2[jp] = bfpair(lv[jp]);
      f32x2 v = l2[jp] + r2[jp];
      t2 += __builtin_elementwise_max(v, NEG_SLOPE * v) * av2[jp];
    }
    float t = t2.x + t2.y;
#pragma unroll
    for (int off = 1; off < 16; off <<= 1) t += __shfl_xor(t, off);
    float es = __expf(t);             // self-loop weight
    denom = (eg == 0) ? es : 0.f;
#pragma unroll
    for (int jp = 0; jp < 4; jp++)
      acc2[jp] = (eg == 0) ? es * l2[jp] : (f32x2){0.f, 0.f};
  }
  const int beg = offsets[node];
  const int end = offsets[node + 1];
  for (int p = beg; p < end; p += 8) {
    int ia = p + 2 * eg;
    bool va = ia < end, vb = ia + 1 < end;
    int sa = va ? (int)ssrc[ia] : node;     // clamp: safe in-bounds row
    int sb = vb ? (int)ssrc[ia + 1] : node;
    u32x4 uva = *(const u32x4*)(xls + (long)sa * 128);
    u32x4 uvb = *(const u32x4*)(xls + (long)sb * 128);
    f32x2 ua2[4], ub2[4];
    f32x2 ta2 = {0.f, 0.f}, tb2 = {0.f, 0.f};
#pragma unroll
    for (int jp = 0; jp < 4; jp++) {
      ua2[jp] = bfpair(uva[jp]);
      ub2[jp] = bfpair(uvb[jp]);
      f32x2 wa = ua2[jp] + r2[jp];
      f32x2 wb = ub2[jp] + r2[jp];
      ta2 += __builtin_elementwise_max(wa, NEG_SLOPE * wa) * av2[jp];
      tb2 += __builtin_elementwise_max(wb, NEG_SLOPE * wb) * av2[jp];
    }
    float ta = ta2.x + ta2.y, tb = tb2.x + tb2.y;
#pragma unroll
    for (int off = 1; off < 16; off <<= 1) {
      ta += __shfl_xor(ta, off);
      tb += __shfl_xor(tb, off);
    }
    float ea = va ? __expf(ta) : 0.f;
    float eb = vb ? __expf(tb) : 0.f;
    denom += ea + eb;
#pragma unroll
    for (int jp = 0; jp < 4; jp++)
      acc2[jp] += ea * ua2[jp] + eb * ub2[jp];
  }
  // combine the 4 edge-subgroup replicas
#pragma unroll
  for (int jp = 0; jp < 4; jp++) {
    acc2[jp].x += __shfl_xor(acc2[jp].x, 16);
    acc2[jp].y += __shfl_xor(acc2[jp].y, 16);
    acc2[jp].x += __shfl_xor(acc2[jp].x, 32);
    acc2[jp].y += __shfl_xor(acc2[jp].y, 32);
  }
  denom += __shfl_xor(denom, 16);
  denom += __shfl_xor(denom, 32);
  if (eg == 0) {
    float inv = 1.0f / denom;
    const float4* bp = (const float4*)(bg + sl * 8);
    float4 g0 = bp[0], g1 = bp[1];
    f32x2 gv[4] = {{g0.x, g0.y}, {g0.z, g0.w}, {g1.x, g1.y}, {g1.z, g1.w}};
    u16x8 o;
#pragma unroll
    for (int jp = 0; jp < 4; jp++) {
      f32x2 hv = acc2[jp] * inv + gv[jp];
      o[2 * jp]     = f2bf(hv.x);
      o[2 * jp + 1] = f2bf(hv.y);
    }
    *(u16x8*)(h + (long)node * 128 + sl * 8) = o;
  }
}

// ---------------------------------------------------------------------------
// k5 (MFMA): out = relu(relu(h@W1+b1)@W2+b2)@W3+b3 ; 32 nodes/block, 4 waves
// (node-group x col-half). Input rows staged into LDS with coalesced loads
// (R7 read them at 256B stride, uncoalesced).
// ---------------------------------------------------------------------------
__global__ __launch_bounds__(256) void mlp_mfma_kernel(
    const ushort* __restrict__ hb,
    const ushort* __restrict__ W1T, const float* __restrict__ b1,
    const ushort* __restrict__ W2T, const float* __restrict__ b2,
    const ushort* __restrict__ W3T, const float* __restrict__ b3,
    float* __restrict__ out, int n) {
  __shared__ ushort act[32][LDSP];
  const int tid = threadIdx.x;
  const int node0 = blockIdx.x * 32;
  for (int i = tid; i < 512; i += 256) {   // 32 rows x 16 u16x8 chunks, coalesced
    int row = i >> 4, c8 = i & 15;
    int node = node0 + row;
    u16x8 v;
    if (node < n) v = *(const u16x8*)(hb + (long)node * 128 + c8 * 8);
    else {
#pragma unroll
      for (int j = 0; j < 8; j++) v[j] = 0;
    }
    *(u16x8*)(&act[row][c8 * 8]) = v;
  }
  __syncthreads();
  const int wv = tid >> 6, lane = tid & 63;
  const int m = lane & 15, quad = lane >> 4;
  const int half = wv & 1, ng = wv >> 1;
  const int colbase = half * 64;
  const int nodew = node0 + ng * 16;
  bf16x8 af[4];
  f32x4 acc[4];
  // ---- layer 1 ----
#pragma unroll
  for (int kk = 0; kk < 4; kk++)
    af[kk] = *(const bf16x8*)(&act[ng * 16 + m][kk * 32 + quad * 8]);
#pragma unroll
  for (int nt = 0; nt < 4; nt++) acc[nt] = (f32x4){0,0,0,0};
#pragma unroll
  for (int kk = 0; kk < 4; kk++) {
    int k0 = kk * 32 + quad * 8;
#pragma unroll
    for (int nt = 0; nt < 4; nt++) {
      bf16x8 b8 = *(const bf16x8*)(W1T + (colbase + nt * 16 + m) * 128 + k0);
      acc[nt] = __builtin_amdgcn_mfma_f32_16x16x32_bf16(af[kk], b8, acc[nt], 0, 0, 0);
    }
  }
  __syncthreads();  // all reads of act done before overwrite
#pragma unroll
  for (int nt = 0; nt < 4; nt++) {
    int col = colbase + nt * 16 + m;
    float b = b1[col];
#pragma unroll
    for (int r = 0; r < 4; r++)
      act[ng * 16 + quad * 4 + r][col] = f2bf(fmaxf(acc[nt][r] + b, 0.f));
  }
  __syncthreads();
  // ---- layer 2 ----
#pragma unroll
  for (int kk = 0; kk < 4; kk++)
    af[kk] = *(const bf16x8*)(&act[ng * 16 + m][kk * 32 + quad * 8]);
#pragma unroll
  for (int nt = 0; nt < 4; nt++) acc[nt] = (f32x4){0,0,0,0};
#pragma unroll
  for (int kk = 0; kk < 4; kk++) {
    int k0 = kk * 32 + quad * 8;
#pragma unroll
    for (int nt = 0; nt < 4; nt++) {
      bf16x8 b8 = *(const bf16x8*)(W2T + (colbase + nt * 16 + m) * 128 + k0);
      acc[nt] = __builtin_amdgcn_mfma_f32_16x16x32_bf16(af[kk], b8, acc[nt], 0, 0, 0);
    }
  }
  __syncthreads();
#pragma unroll
  for (int nt = 0; nt < 4; nt++) {
    int col = colbase + nt * 16 + m;
    float b = b2[col];
#pragma unroll
    for (int r = 0; r < 4; r++)
      act[ng * 16 + quad * 4 + r][col] = f2bf(fmaxf(acc[nt][r] + b, 0.f));
  }
  __syncthreads();
  // ---- layer 3 ----
#pragma unroll
  for (int kk = 0; kk < 4; kk++)
    af[kk] = *(const bf16x8*)(&act[ng * 16 + m][kk * 32 + quad * 8]);
  f32x4 acc3[2];
#pragma unroll
  for (int nt = 0; nt < 2; nt++) acc3[nt] = (f32x4){0,0,0,0};
#pragma unroll
  for (int kk = 0; kk < 4; kk++) {
    int k0 = kk * 32 + quad * 8;
#pragma unroll
    for (int nt = 0; nt < 2; nt++) {
      bf16x8 b8 = *(const bf16x8*)(W3T + (half * 32 + nt * 16 + m) * 128 + k0);
      acc3[nt] = __builtin_amdgcn_mfma_f32_16x16x32_bf16(af[kk], b8, acc3[nt], 0, 0, 0);
    }
  }
#pragma unroll
  for (int nt = 0; nt < 2; nt++) {
    int col = half * 32 + nt * 16 + m;
    float b = b3[col];
#pragma unroll
    for (int r = 0; r < 4; r++) {
      int node = nodew + quad * 4 + r;
      if (node < n) out[(long)node * 64 + col] = acc3[nt][r] + b;
    }
  }
}

extern "C" void kernel_launch(void* const* d_in, const int* in_sizes, int n_in,
                              void* d_out, int out_size, void* d_ws, size_t ws_size,
                              hipStream_t stream) {
  const float* x   = (const float*)d_in[0];
  const int*   ei  = (const int*)d_in[1];
  const float* Wl  = (const float*)d_in[2];
  const float* bl  = (const float*)d_in[3];
  const float* Wr  = (const float*)d_in[4];
  const float* br  = (const float*)d_in[5];
  const float* att = (const float*)d_in[6];
  const float* bg  = (const float*)d_in[7];
  const float* W1  = (const float*)d_in[8];
  const float* b1  = (const float*)d_in[9];
  const float* W2  = (const float*)d_in[10];
  const float* b2  = (const float*)d_in[11];
  const float* W3  = (const float*)d_in[12];
  const float* b3  = (const float*)d_in[13];
  float* out = (float*)d_out;

  const int N = in_sizes[0] / DIN;
  const int E = in_sizes[1] / 2;
  const int nbuck = (N + 255) >> 8;

  // workspace layout, every array 256B-aligned (row gathers must not split
  // cachelines)
  char* ws = (char*)d_ws;
  size_t off = 0;
  auto alloc = [&](size_t bytes) {
    void* p = ws + off;
    off += (bytes + 255) & ~(size_t)255;
    return p;
  };
  int* ghist     = (int*)alloc(256 * 4);
  int* cum       = (int*)alloc(257 * 4);
  int* cursor    = (int*)alloc(256 * 4);
  int* offsets   = (int*)alloc(((size_t)N + 4) * 4);
  unsigned* part = (unsigned*)alloc((size_t)E * 4);
  ushort* ssrc   = (ushort*)alloc(((size_t)E + 32) * 2);
  ushort* xlb    = (ushort*)alloc((size_t)N * DIN * 2);
  ushort* xrb    = (ushort*)alloc((size_t)N * DIN * 2);
  ushort* hbf    = (ushort*)alloc((size_t)N * DIN * 2);
  ushort* WlT    = (ushort*)alloc(16384 * 2);
  ushort* WrT    = (ushort*)alloc(16384 * 2);
  ushort* W1T    = (ushort*)alloc(16384 * 2);
  ushort* W2T    = (ushort*)alloc(16384 * 2);
  ushort* W3T    = (ushort*)alloc(8192 * 2);
  (void)ws_size;

  hipMemsetAsync(ghist, 0, 256 * 4, stream);

  int ntile = (E + PTILE - 1) / PTILE;
  cvt_hist_kernel<<<CVT_BLKS + ntile, 256, 0, stream>>>(
      Wl, Wr, W1, W2, W3, WlT, WrT, W1T, W2T, W3T, ei, ghist, E);

  scan_small_kernel<<<1, 256, 0, stream>>>(ghist, cum, cursor);

  int nblk32 = (N + 31) / 32;
  lin_partition_kernel<<<nblk32 + ntile, 256, 0, stream>>>(
      x, WlT, bl, WrT, br, xlb, xrb, N, nblk32, ei, part, cursor, E);

  fine_kernel<<<nbuck, 1024, 0, stream>>>(part, cum, offsets, ssrc, N, E, nbuck);

  int nwblk = (N + 3) / 4;  // 4 waves (nodes) per 256-thread block
  node_aggr_kernel<<<nwblk, 256, 0, stream>>>(xlb, xrb, att, bg,
                                              offsets, ssrc, hbf, N);

  mlp_mfma_kernel<<<nblk32, 256, 0, stream>>>(hbf, W1T, b1, W2T, b2,
                                              W3T, b3, out, N);
}